// Round 5
// baseline (255.112 us; speedup 1.0000x reference)
//
#include <hip/hip_runtime.h>

// MultiheadAttention: B=2, S=4096, D_MODEL=512, NHEAD=4, HEAD_DIM=128
// R15: flash block 256->512 threads (8 waves, q-tile 256). Per-wave work,
//   LDS layout (48 KB), in-register P, counted vmcnt all unchanged.
//   Rationale: R13 counters show latency-bound (Occ 19%, MfmaUtil 27%,
//   LDS-pipe ~50% util); 8 waves/CU resident was the binder. 512-thr
//   blocks -> 16 waves/CU at the same 2 blocks/CU. DMA issues per thread
//   halve (2 each K/VT -> vmcnt(2) counted waits).
// Keeps: in-register P (cvt_pk+permlane), K dbuf + VT single-buf, fixed-M
//   softmax (Q pre-scaled by 1/sqrt(hd)*log2e), DMA staging w/ global-side
//   XOR swizzle, bh-major grid (XCD L2 locality), K-split 4.

#define D_MODEL 512
#define NHEAD 4
#define HD 128
#define S_ 4096

typedef __attribute__((ext_vector_type(8))) short bf16x8;
typedef __attribute__((ext_vector_type(4))) short bf16x4;
typedef __attribute__((ext_vector_type(4))) float f32x4;
typedef __attribute__((ext_vector_type(2))) unsigned uint2v;
typedef __attribute__((ext_vector_type(4))) unsigned uint4v;

#define SCQ (0.08838834764831845f * 1.4426950408889634f)

__device__ __forceinline__ short f2bf(float f) {
    unsigned u = __builtin_bit_cast(unsigned, f);
    u += 0x7fffu + ((u >> 16) & 1u);
    return (short)(u >> 16);
}
__device__ __forceinline__ unsigned pk2bf(float a, float b) {
    unsigned ua = __builtin_bit_cast(unsigned, a);
    ua += 0x7fffu + ((ua >> 16) & 1u);
    unsigned ub = __builtin_bit_cast(unsigned, b);
    ub += 0x7fffu + ((ub >> 16) & 1u);
    return (ua >> 16) | (ub & 0xffff0000u);
}
__device__ __forceinline__ void gl2lds16(const short* g, short* l) {
    __builtin_amdgcn_global_load_lds(
        (const __attribute__((address_space(1))) void*)g,
        (__attribute__((address_space(3))) void*)l, 16, 0, 0);
}

// ---------------------------------------------------------------------------
// Bulk fp32 -> bf16 conversion. grid.y selects segment; 8 elems/thread.
// ---------------------------------------------------------------------------
__global__ __launch_bounds__(256) void convert_kernel(
    const float* __restrict__ s0, const float* __restrict__ s1,
    const float* __restrict__ s2, const float* __restrict__ s3,
    const float* __restrict__ s4, const float* __restrict__ s5,
    const float* __restrict__ s6,
    short* __restrict__ d0, short* __restrict__ d1, short* __restrict__ d2,
    short* __restrict__ d3, short* __restrict__ d4, short* __restrict__ d5,
    short* __restrict__ d6)
{
    int seg = blockIdx.y;
    const float* src; short* dst; int n;
    const int NBIG = 2 * S_ * D_MODEL;
    const int NW = D_MODEL * D_MODEL;
    switch (seg) {
        case 0: src = s0; dst = d0; n = NBIG; break;
        case 1: src = s1; dst = d1; n = NBIG; break;
        case 2: src = s2; dst = d2; n = NBIG; break;
        case 3: src = s3; dst = d3; n = NW; break;
        case 4: src = s4; dst = d4; n = NW; break;
        case 5: src = s5; dst = d5; n = NW; break;
        default: src = s6; dst = d6; n = NW; break;
    }
    int idx = (blockIdx.x * 256 + threadIdx.x) * 8;
    if (idx >= n) return;
    float4 a = *(const float4*)(src + idx);
    float4 b = *(const float4*)(src + idx + 4);
    uint4v o;
    o[0] = pk2bf(a.x, a.y); o[1] = pk2bf(a.z, a.w);
    o[2] = pk2bf(b.x, b.y); o[3] = pk2bf(b.z, b.w);
    *(uint4v*)(dst + idx) = o;
}

// ---------------------------------------------------------------------------
// Fused QKV projection (bf16 in). 64x128 tiles, BK=64, DMA staging.
// z=0 -> Q[b][h][s][d] (PRE-SCALED by SCQ), z=1 -> K, z=2 -> V^T.
// ---------------------------------------------------------------------------
__global__ __launch_bounds__(256) void qkv_kernel(
    const short* __restrict__ qb, const short* __restrict__ kb,
    const short* __restrict__ vb,
    const short* __restrict__ Wqb, const short* __restrict__ Wkb,
    const short* __restrict__ Wvb,
    const float* __restrict__ bq, const float* __restrict__ bk,
    const float* __restrict__ bv,
    short* __restrict__ Qh, short* __restrict__ Kh, short* __restrict__ VT)
{
    __shared__ short smem[12288];           // 24 KB
    short* lA = smem;                       // 64x64
    short* lB = smem + 4096;                // 128x64
    int z = blockIdx.z;
    const short* A    = (z == 0) ? qb  : (z == 1) ? kb  : vb;
    const short* W    = (z == 0) ? Wqb : (z == 1) ? Wkb : Wvb;
    const float* bias = (z == 0) ? bq  : (z == 1) ? bk  : bv;
    short* out        = (z == 0) ? Qh  : (z == 1) ? Kh  : VT;
    int vmode = (z == 2);
    float osc = (z == 0) ? SCQ : 1.0f;      // Q pre-scale

    int t = threadIdx.x;
    int wv = t >> 6, ln = t & 63, q4 = ln >> 4, c = ln & 15;
    int m0 = blockIdx.x * 64, n0 = blockIdx.y * 128;
    f32x4 acc[8] = {};

    for (int k0 = 0; k0 < 512; k0 += 64) {
        for (int i = 0; i < 2; ++i) {       // A: 512 granules
            int id = i * 256 + t;
            int m = id >> 3, kgp = id & 7;
            gl2lds16(A + (size_t)(m0 + m) * 512 + k0 + ((kgp ^ (m & 7)) << 3),
                     &lA[id * 8]);
        }
        for (int i = 0; i < 4; ++i) {       // B: 1024 granules
            int id = i * 256 + t;
            int n = id >> 3, kgp = id & 7;
            gl2lds16(W + (size_t)(n0 + n) * 512 + k0 + ((kgp ^ (n & 7)) << 3),
                     &lB[id * 8]);
        }
        __syncthreads();
        for (int ks = 0; ks < 2; ++ks) {
            int kg = ks * 4 + q4;
            int m = wv * 16 + c;
            bf16x8 af = *(bf16x8*)&lA[m * 64 + ((kg ^ (m & 7)) << 3)];
            bf16x8 bfr[8];
            for (int nt = 0; nt < 8; ++nt) {
                int n = nt * 16 + c;
                bfr[nt] = *(bf16x8*)&lB[n * 64 + ((kg ^ (n & 7)) << 3)];
            }
            for (int nt = 0; nt < 8; ++nt)
                acc[nt] = __builtin_amdgcn_mfma_f32_16x16x32_bf16(af, bfr[nt], acc[nt], 0, 0, 0);
        }
        __syncthreads();
    }

    if (vmode == 0) {
        // transpose through LDS -> coalesced 16B row stores
        const int TS = 136;
        short* lT = smem;                    // 64 x 136 = 17408 B
        for (int nt = 0; nt < 8; ++nt) {
            float bv_ = bias[n0 + nt * 16 + c];
            for (int r = 0; r < 4; ++r) {
                int srow = wv * 16 + q4 * 4 + r;
                lT[srow * TS + nt * 16 + c] = f2bf((acc[nt][r] + bv_) * osc);
            }
        }
        __syncthreads();
        int bb = m0 >> 12, sbase = m0 & 4095, h = blockIdx.y;
        for (int i = 0; i < 4; ++i) {        // 64 rows x 16 granules
            int id = i * 256 + t;
            int row = id >> 4, g = id & 15;
            bf16x8 vv = *(bf16x8*)&lT[row * TS + g * 8];
            *(bf16x8*)&out[((size_t)((bb * NHEAD + h) * S_ + sbase + row)) * HD + g * 8] = vv;
        }
    } else {
        for (int nt = 0; nt < 8; ++nt) {
            int d = nt * 16 + c;
            float bv_ = bias[n0 + d];
            uint2v pv;
            pv[0] = pk2bf(acc[nt][0] + bv_, acc[nt][1] + bv_);
            pv[1] = pk2bf(acc[nt][2] + bv_, acc[nt][3] + bv_);
            int gr = wv * 4 + q4;
            *(uint2v*)&lB[d * 64 + ((gr ^ (d & 15)) << 2)] = pv;
        }
        __syncthreads();
        int bb = m0 >> 12, sbase = m0 & 4095, h = blockIdx.y;
        for (int i = 0; i < 8; ++i) {
            int id = i * 256 + t;
            int d = id >> 4, grl = id & 15;
            bf16x4 v = *(bf16x4*)&lB[d * 64 + ((grl ^ (d & 15)) << 2)];
            *(bf16x4*)&out[((size_t)((bb * NHEAD + h) * HD + d)) * S_ + sbase + grl * 4] = v;
        }
    }
}

// ---------------------------------------------------------------------------
// Output projection (bf16 AO, bf16 Wo): 64x128 tiles, BK=64, DMA staging.
// ---------------------------------------------------------------------------
__global__ __launch_bounds__(256) void outproj_kernel(
    const short* __restrict__ A, const short* __restrict__ W,
    const float* __restrict__ bias, float* __restrict__ out)
{
    __shared__ short lA[64 * 64];
    __shared__ short lB[128 * 64];
    int t = threadIdx.x;
    int wv = t >> 6, ln = t & 63, q4 = ln >> 4, c = ln & 15;
    int m0 = blockIdx.x * 64, n0 = blockIdx.y * 128;
    f32x4 acc[8] = {};

    for (int k0 = 0; k0 < 512; k0 += 64) {
        for (int i = 0; i < 2; ++i) {
            int id = i * 256 + t;
            int m = id >> 3, kgp = id & 7;
            gl2lds16(A + (size_t)(m0 + m) * 512 + k0 + ((kgp ^ (m & 7)) << 3),
                     &lA[id * 8]);
        }
        for (int i = 0; i < 4; ++i) {
            int id = i * 256 + t;
            int n = id >> 3, kgp = id & 7;
            gl2lds16(W + (size_t)(n0 + n) * 512 + k0 + ((kgp ^ (n & 7)) << 3),
                     &lB[id * 8]);
        }
        __syncthreads();
        for (int ks = 0; ks < 2; ++ks) {
            int kg = ks * 4 + q4;
            int m = wv * 16 + c;
            bf16x8 af = *(bf16x8*)&lA[m * 64 + ((kg ^ (m & 7)) << 3)];
            bf16x8 bfr[8];
            for (int nt = 0; nt < 8; ++nt) {
                int n = nt * 16 + c;
                bfr[nt] = *(bf16x8*)&lB[n * 64 + ((kg ^ (n & 7)) << 3)];
            }
            for (int nt = 0; nt < 8; ++nt)
                acc[nt] = __builtin_amdgcn_mfma_f32_16x16x32_bf16(af, bfr[nt], acc[nt], 0, 0, 0);
        }
        __syncthreads();
    }

    for (int nt = 0; nt < 8; ++nt) {
        int col = n0 + nt * 16 + c;
        float bv_ = bias[col];
        for (int r = 0; r < 4; ++r) {
            int mrow = m0 + wv * 16 + q4 * 4 + r;
            out[(size_t)mrow * 512 + col] = acc[nt][r] + bv_;
        }
    }
}

// ---------------------------------------------------------------------------
// Flash attention: 8-wave q-split (q-tile 256), K dbuf, VT single-buf,
// in-register P (cvt_pk + permlane swaps), counted vmcnt, 2 barriers/tile.
// grid = (bh 8, qtile 16, z nsplit), block = 512
// ---------------------------------------------------------------------------
__global__ __launch_bounds__(512, 2) void flash_kernel(
    const short* __restrict__ Qh, const short* __restrict__ Kh,
    const short* __restrict__ VTg, short* __restrict__ AO,
    float* __restrict__ U, float* __restrict__ ML, int nsplit, int kkspan)
{
    __shared__ short lK[2][64 * 128];   // 2 x 16 KB
    __shared__ short lVT[128 * 64];     // 16 KB
    int t = threadIdx.x;
    int wv = t >> 6, ln = t & 63, q4 = ln >> 4, c = ln & 15;
    int bh = blockIdx.x;
    int s0 = blockIdx.y * 256;
    int z = blockIdx.z;
    const size_t base = (size_t)bh * S_ * HD;

    // Q fragments: wave wv owns q rows [s0+32*wv, +32)
    bf16x8 qf[2][4];
    #pragma unroll
    for (int qt = 0; qt < 2; ++qt) {
        int s = s0 + wv * 32 + qt * 16 + c;
        const short* qp = Qh + base + (size_t)s * HD + q4 * 8;
        #pragma unroll
        for (int ks = 0; ks < 4; ++ks)
            qf[qt][ks] = *(const bf16x8*)(qp + ks * 32);
    }

    f32x4 of[8][2] = {};      // of[dt][qt]: d = dt*16+q4*4+r, q = c
    float lrun[2] = {};

    int kkbeg = z * kkspan;
    int nt = kkspan >> 6;

    // ---- prologue: stage tile 0 (K -> lK[0], VT -> lVT) ----
    #pragma unroll
    for (int i = 0; i < 2; ++i) {
        int id = i * 512 + t;
        int m = id >> 4, kgp = id & 15;
        gl2lds16(Kh + base + (size_t)(kkbeg + m) * HD + ((kgp ^ (m & 7)) << 3),
                 &lK[0][id * 8]);
    }
    #pragma unroll
    for (int i = 0; i < 2; ++i) {
        int id = i * 512 + t;
        int mv = id >> 3, kgvp = id & 7;
        gl2lds16(VTg + base + (size_t)mv * S_ + kkbeg + ((kgvp ^ (mv & 7)) << 3),
                 &lVT[id * 8]);
    }
    asm volatile("s_waitcnt vmcnt(2)" ::: "memory");  // K(0) landed, VT(0) in flight
    __builtin_amdgcn_s_barrier();
    __builtin_amdgcn_sched_barrier(0);

    int cur = 0;
    for (int it = 0; it < nt; ++it) {
        int kk0 = kkbeg + it * 64;
        int more = (it + 1 < nt);

        // stage K(t+1) -> lK[cur^1]; in flight across the whole compute phase
        if (more) {
            #pragma unroll
            for (int i = 0; i < 2; ++i) {
                int id = i * 512 + t;
                int m = id >> 4, kgp = id & 15;
                gl2lds16(Kh + base + (size_t)(kk0 + 64 + m) * HD + ((kgp ^ (m & 7)) << 3),
                         &lK[cur ^ 1][id * 8]);
            }
        }

        // QK^T: sf[qt][kt] — all 64 keys for this wave's 32 q rows
        f32x4 sf[2][4] = {};
        __builtin_amdgcn_s_setprio(1);
        #pragma unroll
        for (int ks = 0; ks < 4; ++ks) {
            int kg = ks * 4 + q4;
            bf16x8 af[4];
            #pragma unroll
            for (int kt = 0; kt < 4; ++kt) {
                int row = kt * 16 + c;
                af[kt] = *(bf16x8*)&lK[cur][row * 128 + ((kg ^ (row & 7)) << 3)];
            }
            #pragma unroll
            for (int qt = 0; qt < 2; ++qt)
                #pragma unroll
                for (int kt = 0; kt < 4; ++kt)
                    sf[qt][kt] = __builtin_amdgcn_mfma_f32_16x16x32_bf16(
                        af[kt], qf[qt][ks], sf[qt][kt], 0, 0, 0);
        }
        __builtin_amdgcn_s_setprio(0);

        // fixed-M softmax + in-register P->B-frag redistribution.
        // Lane(q4,c) after QK^T: P[key=kt*16+q4*4+r][q=c] in sf[qt][kt][r].
        // Target B-frag (bf16x8): lane(q4,c) holds keys ksv*32+q4*8..+7.
        // X=[X0,X1,X2,X3],Y per 16-lane rows; p32swap -> [X0,X1,Y0,Y1],
        // [X2,X3,Y2,Y3]; p16swap -> Z=[X0,X2,Y0,Y2], W=[X1,X3,Y1,Y3].
        bf16x8 bp[2][2];
        #pragma unroll
        for (int qt = 0; qt < 2; ++qt) {
            unsigned dlo[4], dhi[4];
            float lt = 0.f;
            #pragma unroll
            for (int kt = 0; kt < 4; ++kt) {
                float p0 = exp2f(sf[qt][kt][0]);
                float p1 = exp2f(sf[qt][kt][1]);
                float p2 = exp2f(sf[qt][kt][2]);
                float p3 = exp2f(sf[qt][kt][3]);
                lt += (p0 + p1) + (p2 + p3);
                asm("v_cvt_pk_bf16_f32 %0, %1, %2" : "=v"(dlo[kt]) : "v"(p0), "v"(p1));
                asm("v_cvt_pk_bf16_f32 %0, %1, %2" : "=v"(dhi[kt]) : "v"(p2), "v"(p3));
            }
            lrun[qt] += lt;            // lane-partial; cross-lane reduce deferred
            #pragma unroll
            for (int ksv = 0; ksv < 2; ++ksv) {
                unsigned x0 = dlo[2 * ksv], y0 = dlo[2 * ksv + 1];
                unsigned x1 = dhi[2 * ksv], y1 = dhi[2 * ksv + 1];
                asm("v_permlane32_swap_b32 %0, %1" : "+v"(x0), "+v"(y0));
                asm("v_permlane16_swap_b32 %0, %1" : "+v"(x0), "+v"(y0));
                asm("v_permlane32_swap_b32 %0, %1" : "+v"(x1), "+v"(y1));
                asm("v_permlane16_swap_b32 %0, %1" : "+v"(x1), "+v"(y1));
                uint4v u; u[0] = x0; u[1] = x1; u[2] = y0; u[3] = y1;
                bp[qt][ksv] = __builtin_bit_cast(bf16x8, u);
            }
        }

        // mid barrier: VT(t) must be landed; K(t+1) stays in flight
        if (more) asm volatile("s_waitcnt vmcnt(2)" ::: "memory");
        else      asm volatile("s_waitcnt vmcnt(0)" ::: "memory");
        __builtin_amdgcn_s_barrier();
        __builtin_amdgcn_sched_barrier(0);

        // PV: of[dt][qt] += VT[d][k] @ P[k][q]  (P from registers)
        __builtin_amdgcn_s_setprio(1);
        #pragma unroll
        for (int ksv = 0; ksv < 2; ++ksv) {
            int kg = ksv * 4 + q4;
            bf16x8 av[8];
            #pragma unroll
            for (int dt = 0; dt < 8; ++dt) {
                int row = dt * 16 + c;
                av[dt] = *(bf16x8*)&lVT[row * 64 + ((kg ^ (row & 7)) << 3)];
            }
            #pragma unroll
            for (int qt = 0; qt < 2; ++qt)
                #pragma unroll
                for (int dt = 0; dt < 8; ++dt)
                    of[dt][qt] = __builtin_amdgcn_mfma_f32_16x16x32_bf16(
                        av[dt], bp[qt][ksv], of[dt][qt], 0, 0, 0);
        }
        __builtin_amdgcn_s_setprio(0);

        // end barrier: K(t+1) landed; all waves done reading lVT
        asm volatile("s_waitcnt vmcnt(0)" ::: "memory");
        __builtin_amdgcn_s_barrier();
        __builtin_amdgcn_sched_barrier(0);

        if (more) {
            #pragma unroll
            for (int i = 0; i < 2; ++i) {
                int id = i * 512 + t;
                int mv = id >> 3, kgvp = id & 7;
                gl2lds16(VTg + base + (size_t)mv * S_ + kk0 + 64 + ((kgvp ^ (mv & 7)) << 3),
                         &lVT[id * 8]);
            }
        }
        cur ^= 1;
    }

    // deferred cross-lane l reduction (sum over q4 groups for fixed q=c)
    #pragma unroll
    for (int qt = 0; qt < 2; ++qt) {
        lrun[qt] += __shfl_xor(lrun[qt], 16);
        lrun[qt] += __shfl_xor(lrun[qt], 32);
    }

    if (nsplit > 1) {
        #pragma unroll
        for (int qt = 0; qt < 2; ++qt) {
            int s = s0 + wv * 32 + qt * 16 + c;
            size_t rowu = (size_t)(z * 8 + bh) * S_ + s;
            float* up = U + rowu * HD;
            #pragma unroll
            for (int dt = 0; dt < 8; ++dt)
                *(f32x4*)&up[dt * 16 + q4 * 4] = of[dt][qt];
            if (q4 == 0) ML[rowu] = lrun[qt];
        }
    } else {
        int b = bh >> 2, h = bh & 3;
        #pragma unroll
        for (int qt = 0; qt < 2; ++qt) {
            float inv = 1.0f / lrun[qt];
            int s = s0 + wv * 32 + qt * 16 + c;
            short* dst = AO + ((size_t)(b * S_ + s)) * D_MODEL + h * HD;
            #pragma unroll
            for (int dt = 0; dt < 8; ++dt) {
                uint2v ov;
                ov[0] = pk2bf(of[dt][qt][0] * inv, of[dt][qt][1] * inv);
                ov[1] = pk2bf(of[dt][qt][2] * inv, of[dt][qt][3] * inv);
                *(uint2v*)(dst + dt * 16 + q4 * 4) = ov;
            }
        }
    }
}

// ---------------------------------------------------------------------------
// Combine nsplit K-split partials (fixed-M): O = sum(Uz)/sum(lz) -> bf16 AO
// ---------------------------------------------------------------------------
__global__ __launch_bounds__(256) void combine_kernel(
    const float* __restrict__ U, const float* __restrict__ ML,
    short* __restrict__ AO, int nsplit)
{
    int row = blockIdx.x * 8 + (threadIdx.x >> 5);
    int d4 = (threadIdx.x & 31) * 4;
    const int R = 8 * S_;
    float l = 0.f;
    f32x4 u = {0.f, 0.f, 0.f, 0.f};
    for (int zz = 0; zz < nsplit; ++zz) {
        l += ML[(size_t)zz * R + row];
        f32x4 uz = *(const f32x4*)&U[((size_t)zz * R + row) * HD + d4];
        u += uz;
    }
    float inv = 1.0f / l;
    uint2v o;
    o[0] = pk2bf(u[0] * inv, u[1] * inv);
    o[1] = pk2bf(u[2] * inv, u[3] * inv);
    int bh = row >> 12, s = row & 4095;
    int b = bh >> 2, h = bh & 3;
    *(uint2v*)&AO[((size_t)(b * S_ + s)) * D_MODEL + h * HD + d4] = o;
}

// ---------------------------------------------------------------------------
extern "C" void kernel_launch(void* const* d_in, const int* in_sizes, int n_in,
                              void* d_out, int out_size, void* d_ws, size_t ws_size,
                              hipStream_t stream) {
    const float* q  = (const float*)d_in[0];
    const float* k  = (const float*)d_in[1];
    const float* v  = (const float*)d_in[2];
    const float* Wq = (const float*)d_in[3];
    const float* bq = (const float*)d_in[4];
    const float* Wk = (const float*)d_in[5];
    const float* bk = (const float*)d_in[6];
    const float* Wv = (const float*)d_in[7];
    const float* bv = (const float*)d_in[8];
    const float* Wo = (const float*)d_in[9];
    const float* bo = (const float*)d_in[10];

    const size_t HS = (size_t)2 * NHEAD * S_ * HD;      // 4,194,304 elems
    const size_t NBIG = HS;
    const size_t NW = (size_t)D_MODEL * D_MODEL;
    const size_t R = (size_t)8 * S_;                     // U rows per split

    char* wsb = (char*)d_ws;
    short* Qh = (short*)wsb;
    short* Kh = Qh + HS;
    short* VT = Kh + HS;
    short* AO = VT + HS;
    char* r2 = wsb + 4 * HS * 2;
    short* qb  = (short*)r2;
    short* kb  = qb + NBIG;
    short* vb  = kb + NBIG;
    short* Wqb = vb + NBIG;
    short* Wkb = Wqb + NW;
    short* Wvb = Wkb + NW;
    float* U   = (float*)r2;

    // pick largest nsplit whose workspace fits
    int nsplit = 1;
    size_t r2sz = 3 * NBIG * 2 + 3 * NW * 2;            // bf16 temps floor
    for (int cand = 4; cand >= 2; cand -= 2) {
        size_t r2c = (size_t)cand * R * HD * 4;         // U bytes
        if (r2c < 3 * NBIG * 2 + 3 * NW * 2) r2c = 3 * NBIG * 2 + 3 * NW * 2;
        size_t need = 4 * HS * 2 + r2c + (size_t)cand * R * 4 + NW * 2;
        if (ws_size >= need) { nsplit = cand; r2sz = r2c; break; }
    }
    float* ML  = (float*)(r2 + r2sz);
    short* Wob = (short*)((char*)ML + (size_t)nsplit * R * 4);
    int kkspan = S_ / nsplit;

    dim3 blk(256);
    convert_kernel<<<dim3(2048, 7), blk, 0, stream>>>(
        q, k, v, Wq, Wk, Wv, Wo, qb, kb, vb, Wqb, Wkb, Wvb, Wob);
    qkv_kernel<<<dim3(128, 4, 3), blk, 0, stream>>>(
        qb, kb, vb, Wqb, Wkb, Wvb, bq, bk, bv, Qh, Kh, VT);
    flash_kernel<<<dim3(8, 16, nsplit), dim3(512), 0, stream>>>(
        Qh, Kh, VT, AO, U, ML, nsplit, kkspan);
    if (nsplit > 1)
        combine_kernel<<<dim3(S_), blk, 0, stream>>>(U, ML, AO, nsplit);
    outproj_kernel<<<dim3(128, 4), blk, 0, stream>>>(AO, Wob, bo, (float*)d_out);
}

// Round 6
// 228.383 us; speedup vs baseline: 1.1170x; 1.1170x over previous
//
#include <hip/hip_runtime.h>

// MultiheadAttention: B=2, S=4096, D_MODEL=512, NHEAD=4, HEAD_DIM=128
// R16: (a) flash reverted to R13 config (256 thr, q-tile 128) — R15's 512-thr
//   block was neutral-negative (barrier-locked waves don't add latency hiding).
//   (b) qkv/outproj pipelined: A+B double-buffered (48 KB LDS), next-tile DMA
//   issued before compute (in flight across MFMA phase), ONE barrier/K-step,
//   setprio around MFMA. Was: stage -> drain -> compute -> barrier (2/step).
//   (c) nsplit 4->2: flash residency is 2 blocks/CU either way; halves U
//   traffic (64->32 MB) and combine cost.
// Keeps: in-register P (cvt_pk+permlane), K dbuf + VT single-buf flash
//   pipeline w/ counted vmcnt, fixed-M softmax (Q pre-scaled), DMA staging
//   w/ global-side XOR swizzle, bh-major grid.

#define D_MODEL 512
#define NHEAD 4
#define HD 128
#define S_ 4096

typedef __attribute__((ext_vector_type(8))) short bf16x8;
typedef __attribute__((ext_vector_type(4))) short bf16x4;
typedef __attribute__((ext_vector_type(4))) float f32x4;
typedef __attribute__((ext_vector_type(2))) unsigned uint2v;
typedef __attribute__((ext_vector_type(4))) unsigned uint4v;

#define SCQ (0.08838834764831845f * 1.4426950408889634f)

__device__ __forceinline__ short f2bf(float f) {
    unsigned u = __builtin_bit_cast(unsigned, f);
    u += 0x7fffu + ((u >> 16) & 1u);
    return (short)(u >> 16);
}
__device__ __forceinline__ unsigned pk2bf(float a, float b) {
    unsigned ua = __builtin_bit_cast(unsigned, a);
    ua += 0x7fffu + ((ua >> 16) & 1u);
    unsigned ub = __builtin_bit_cast(unsigned, b);
    ub += 0x7fffu + ((ub >> 16) & 1u);
    return (ua >> 16) | (ub & 0xffff0000u);
}
__device__ __forceinline__ void gl2lds16(const short* g, short* l) {
    __builtin_amdgcn_global_load_lds(
        (const __attribute__((address_space(1))) void*)g,
        (__attribute__((address_space(3))) void*)l, 16, 0, 0);
}

// ---------------------------------------------------------------------------
// Bulk fp32 -> bf16 conversion. grid.y selects segment; 8 elems/thread.
// ---------------------------------------------------------------------------
__global__ __launch_bounds__(256) void convert_kernel(
    const float* __restrict__ s0, const float* __restrict__ s1,
    const float* __restrict__ s2, const float* __restrict__ s3,
    const float* __restrict__ s4, const float* __restrict__ s5,
    const float* __restrict__ s6,
    short* __restrict__ d0, short* __restrict__ d1, short* __restrict__ d2,
    short* __restrict__ d3, short* __restrict__ d4, short* __restrict__ d5,
    short* __restrict__ d6)
{
    int seg = blockIdx.y;
    const float* src; short* dst; int n;
    const int NBIG = 2 * S_ * D_MODEL;
    const int NW = D_MODEL * D_MODEL;
    switch (seg) {
        case 0: src = s0; dst = d0; n = NBIG; break;
        case 1: src = s1; dst = d1; n = NBIG; break;
        case 2: src = s2; dst = d2; n = NBIG; break;
        case 3: src = s3; dst = d3; n = NW; break;
        case 4: src = s4; dst = d4; n = NW; break;
        case 5: src = s5; dst = d5; n = NW; break;
        default: src = s6; dst = d6; n = NW; break;
    }
    int idx = (blockIdx.x * 256 + threadIdx.x) * 8;
    if (idx >= n) return;
    float4 a = *(const float4*)(src + idx);
    float4 b = *(const float4*)(src + idx + 4);
    uint4v o;
    o[0] = pk2bf(a.x, a.y); o[1] = pk2bf(a.z, a.w);
    o[2] = pk2bf(b.x, b.y); o[3] = pk2bf(b.z, b.w);
    *(uint4v*)(dst + idx) = o;
}

// ---------------------------------------------------------------------------
// Fused QKV projection (bf16 in). 64x128 tiles, BK=64, A+B double-buffered,
// one barrier per K-step, DMA in flight across compute.
// z=0 -> Q[b][h][s][d] (PRE-SCALED by SCQ), z=1 -> K, z=2 -> V^T.
// ---------------------------------------------------------------------------
__global__ __launch_bounds__(256) void qkv_kernel(
    const short* __restrict__ qb, const short* __restrict__ kb,
    const short* __restrict__ vb,
    const short* __restrict__ Wqb, const short* __restrict__ Wkb,
    const short* __restrict__ Wvb,
    const float* __restrict__ bq, const float* __restrict__ bk,
    const float* __restrict__ bv,
    short* __restrict__ Qh, short* __restrict__ Kh, short* __restrict__ VT)
{
    __shared__ short smem[24576];           // 48 KB
    // lA[cur] = smem + cur*4096 (64x64), lB[cur] = smem + 8192 + cur*8192
    int z = blockIdx.z;
    const short* A    = (z == 0) ? qb  : (z == 1) ? kb  : vb;
    const short* W    = (z == 0) ? Wqb : (z == 1) ? Wkb : Wvb;
    const float* bias = (z == 0) ? bq  : (z == 1) ? bk  : bv;
    short* out        = (z == 0) ? Qh  : (z == 1) ? Kh  : VT;
    int vmode = (z == 2);
    float osc = (z == 0) ? SCQ : 1.0f;      // Q pre-scale

    int t = threadIdx.x;
    int wv = t >> 6, ln = t & 63, q4 = ln >> 4, c = ln & 15;
    int m0 = blockIdx.x * 64, n0 = blockIdx.y * 128;
    f32x4 acc[8] = {};

    // prologue: stage k0=0 into buf 0
    {
        short* lAd = smem;
        short* lBd = smem + 8192;
        #pragma unroll
        for (int i = 0; i < 2; ++i) {
            int id = i * 256 + t;
            int m = id >> 3, kgp = id & 7;
            gl2lds16(A + (size_t)(m0 + m) * 512 + ((kgp ^ (m & 7)) << 3), &lAd[id * 8]);
        }
        #pragma unroll
        for (int i = 0; i < 4; ++i) {
            int id = i * 256 + t;
            int n = id >> 3, kgp = id & 7;
            gl2lds16(W + (size_t)(n0 + n) * 512 + ((kgp ^ (n & 7)) << 3), &lBd[id * 8]);
        }
    }
    asm volatile("s_waitcnt vmcnt(0)" ::: "memory");
    __builtin_amdgcn_s_barrier();
    __builtin_amdgcn_sched_barrier(0);

    int cur = 0;
    for (int k0 = 0; k0 < 512; k0 += 64) {
        int more = (k0 < 448);
        if (more) {
            short* lAd = smem + (cur ^ 1) * 4096;
            short* lBd = smem + 8192 + (cur ^ 1) * 8192;
            int kn = k0 + 64;
            #pragma unroll
            for (int i = 0; i < 2; ++i) {
                int id = i * 256 + t;
                int m = id >> 3, kgp = id & 7;
                gl2lds16(A + (size_t)(m0 + m) * 512 + kn + ((kgp ^ (m & 7)) << 3), &lAd[id * 8]);
            }
            #pragma unroll
            for (int i = 0; i < 4; ++i) {
                int id = i * 256 + t;
                int n = id >> 3, kgp = id & 7;
                gl2lds16(W + (size_t)(n0 + n) * 512 + kn + ((kgp ^ (n & 7)) << 3), &lBd[id * 8]);
            }
        }
        short* lAc = smem + cur * 4096;
        short* lBc = smem + 8192 + cur * 8192;
        __builtin_amdgcn_s_setprio(1);
        #pragma unroll
        for (int ks = 0; ks < 2; ++ks) {
            int kg = ks * 4 + q4;
            int m = wv * 16 + c;
            bf16x8 af = *(bf16x8*)&lAc[m * 64 + ((kg ^ (m & 7)) << 3)];
            bf16x8 bfr[8];
            #pragma unroll
            for (int nt = 0; nt < 8; ++nt) {
                int n = nt * 16 + c;
                bfr[nt] = *(bf16x8*)&lBc[n * 64 + ((kg ^ (n & 7)) << 3)];
            }
            #pragma unroll
            for (int nt = 0; nt < 8; ++nt)
                acc[nt] = __builtin_amdgcn_mfma_f32_16x16x32_bf16(af, bfr[nt], acc[nt], 0, 0, 0);
        }
        __builtin_amdgcn_s_setprio(0);
        if (more) asm volatile("s_waitcnt vmcnt(0)" ::: "memory");
        __builtin_amdgcn_s_barrier();
        __builtin_amdgcn_sched_barrier(0);
        cur ^= 1;
    }

    if (vmode == 0) {
        // transpose through LDS -> coalesced 16B row stores
        const int TS = 136;
        short* lT = smem;                    // 64 x 136 = 17408 B
        for (int nt = 0; nt < 8; ++nt) {
            float bv_ = bias[n0 + nt * 16 + c];
            for (int r = 0; r < 4; ++r) {
                int srow = wv * 16 + q4 * 4 + r;
                lT[srow * TS + nt * 16 + c] = f2bf((acc[nt][r] + bv_) * osc);
            }
        }
        __syncthreads();
        int bb = m0 >> 12, sbase = m0 & 4095, h = blockIdx.y;
        for (int i = 0; i < 4; ++i) {        // 64 rows x 16 granules
            int id = i * 256 + t;
            int row = id >> 4, g = id & 15;
            bf16x8 vv = *(bf16x8*)&lT[row * TS + g * 8];
            *(bf16x8*)&out[((size_t)((bb * NHEAD + h) * S_ + sbase + row)) * HD + g * 8] = vv;
        }
    } else {
        short* lB0 = smem + 8192;
        for (int nt = 0; nt < 8; ++nt) {
            int d = nt * 16 + c;
            float bv_ = bias[n0 + d];
            uint2v pv;
            pv[0] = pk2bf(acc[nt][0] + bv_, acc[nt][1] + bv_);
            pv[1] = pk2bf(acc[nt][2] + bv_, acc[nt][3] + bv_);
            int gr = wv * 4 + q4;
            *(uint2v*)&lB0[d * 64 + ((gr ^ (d & 15)) << 2)] = pv;
        }
        __syncthreads();
        int bb = m0 >> 12, sbase = m0 & 4095, h = blockIdx.y;
        for (int i = 0; i < 8; ++i) {
            int id = i * 256 + t;
            int d = id >> 4, grl = id & 15;
            bf16x4 v = *(bf16x4*)&lB0[d * 64 + ((grl ^ (d & 15)) << 2)];
            *(bf16x4*)&out[((size_t)((bb * NHEAD + h) * HD + d)) * S_ + sbase + grl * 4] = v;
        }
    }
}

// ---------------------------------------------------------------------------
// Output projection (bf16 AO, bf16 Wo): 64x128 tiles, BK=64, A+B dbuf,
// one barrier per K-step.
// ---------------------------------------------------------------------------
__global__ __launch_bounds__(256) void outproj_kernel(
    const short* __restrict__ A, const short* __restrict__ W,
    const float* __restrict__ bias, float* __restrict__ out)
{
    __shared__ short smem[24576];           // 48 KB
    int t = threadIdx.x;
    int wv = t >> 6, ln = t & 63, q4 = ln >> 4, c = ln & 15;
    int m0 = blockIdx.x * 64, n0 = blockIdx.y * 128;
    f32x4 acc[8] = {};

    {
        short* lAd = smem;
        short* lBd = smem + 8192;
        #pragma unroll
        for (int i = 0; i < 2; ++i) {
            int id = i * 256 + t;
            int m = id >> 3, kgp = id & 7;
            gl2lds16(A + (size_t)(m0 + m) * 512 + ((kgp ^ (m & 7)) << 3), &lAd[id * 8]);
        }
        #pragma unroll
        for (int i = 0; i < 4; ++i) {
            int id = i * 256 + t;
            int n = id >> 3, kgp = id & 7;
            gl2lds16(W + (size_t)(n0 + n) * 512 + ((kgp ^ (n & 7)) << 3), &lBd[id * 8]);
        }
    }
    asm volatile("s_waitcnt vmcnt(0)" ::: "memory");
    __builtin_amdgcn_s_barrier();
    __builtin_amdgcn_sched_barrier(0);

    int cur = 0;
    for (int k0 = 0; k0 < 512; k0 += 64) {
        int more = (k0 < 448);
        if (more) {
            short* lAd = smem + (cur ^ 1) * 4096;
            short* lBd = smem + 8192 + (cur ^ 1) * 8192;
            int kn = k0 + 64;
            #pragma unroll
            for (int i = 0; i < 2; ++i) {
                int id = i * 256 + t;
                int m = id >> 3, kgp = id & 7;
                gl2lds16(A + (size_t)(m0 + m) * 512 + kn + ((kgp ^ (m & 7)) << 3), &lAd[id * 8]);
            }
            #pragma unroll
            for (int i = 0; i < 4; ++i) {
                int id = i * 256 + t;
                int n = id >> 3, kgp = id & 7;
                gl2lds16(W + (size_t)(n0 + n) * 512 + kn + ((kgp ^ (n & 7)) << 3), &lBd[id * 8]);
            }
        }
        short* lAc = smem + cur * 4096;
        short* lBc = smem + 8192 + cur * 8192;
        __builtin_amdgcn_s_setprio(1);
        #pragma unroll
        for (int ks = 0; ks < 2; ++ks) {
            int kg = ks * 4 + q4;
            int m = wv * 16 + c;
            bf16x8 af = *(bf16x8*)&lAc[m * 64 + ((kg ^ (m & 7)) << 3)];
            bf16x8 bfr[8];
            #pragma unroll
            for (int nt = 0; nt < 8; ++nt) {
                int n = nt * 16 + c;
                bfr[nt] = *(bf16x8*)&lBc[n * 64 + ((kg ^ (n & 7)) << 3)];
            }
            #pragma unroll
            for (int nt = 0; nt < 8; ++nt)
                acc[nt] = __builtin_amdgcn_mfma_f32_16x16x32_bf16(af, bfr[nt], acc[nt], 0, 0, 0);
        }
        __builtin_amdgcn_s_setprio(0);
        if (more) asm volatile("s_waitcnt vmcnt(0)" ::: "memory");
        __builtin_amdgcn_s_barrier();
        __builtin_amdgcn_sched_barrier(0);
        cur ^= 1;
    }

    for (int nt = 0; nt < 8; ++nt) {
        int col = n0 + nt * 16 + c;
        float bv_ = bias[col];
        for (int r = 0; r < 4; ++r) {
            int mrow = m0 + wv * 16 + q4 * 4 + r;
            out[(size_t)mrow * 512 + col] = acc[nt][r] + bv_;
        }
    }
}

// ---------------------------------------------------------------------------
// Flash attention: 4-wave q-split, K dbuf, VT single-buf, in-register P
// (cvt_pk + permlane swaps), counted vmcnt, 2 barriers/tile.
// grid = (bh 8, qtile 32, z nsplit)
// ---------------------------------------------------------------------------
__global__ __launch_bounds__(256, 2) void flash_kernel(
    const short* __restrict__ Qh, const short* __restrict__ Kh,
    const short* __restrict__ VTg, short* __restrict__ AO,
    float* __restrict__ U, float* __restrict__ ML, int nsplit, int kkspan)
{
    __shared__ short lK[2][64 * 128];   // 2 x 16 KB
    __shared__ short lVT[128 * 64];     // 16 KB
    int t = threadIdx.x;
    int wv = t >> 6, ln = t & 63, q4 = ln >> 4, c = ln & 15;
    int bh = blockIdx.x;
    int s0 = blockIdx.y * 128;
    int z = blockIdx.z;
    const size_t base = (size_t)bh * S_ * HD;

    // Q fragments: wave wv owns q rows [s0+32*wv, +32)
    bf16x8 qf[2][4];
    #pragma unroll
    for (int qt = 0; qt < 2; ++qt) {
        int s = s0 + wv * 32 + qt * 16 + c;
        const short* qp = Qh + base + (size_t)s * HD + q4 * 8;
        #pragma unroll
        for (int ks = 0; ks < 4; ++ks)
            qf[qt][ks] = *(const bf16x8*)(qp + ks * 32);
    }

    f32x4 of[8][2] = {};      // of[dt][qt]: d = dt*16+q4*4+r, q = c
    float lrun[2] = {};

    int kkbeg = z * kkspan;
    int nt = kkspan >> 6;

    // ---- prologue: stage tile 0 (K -> lK[0], VT -> lVT) ----
    #pragma unroll
    for (int i = 0; i < 4; ++i) {
        int id = i * 256 + t;
        int m = id >> 4, kgp = id & 15;
        gl2lds16(Kh + base + (size_t)(kkbeg + m) * HD + ((kgp ^ (m & 7)) << 3),
                 &lK[0][id * 8]);
    }
    #pragma unroll
    for (int i = 0; i < 4; ++i) {
        int id = i * 256 + t;
        int mv = id >> 3, kgvp = id & 7;
        gl2lds16(VTg + base + (size_t)mv * S_ + kkbeg + ((kgvp ^ (mv & 7)) << 3),
                 &lVT[id * 8]);
    }
    asm volatile("s_waitcnt vmcnt(4)" ::: "memory");  // K(0) landed, VT(0) in flight
    __builtin_amdgcn_s_barrier();
    __builtin_amdgcn_sched_barrier(0);

    int cur = 0;
    for (int it = 0; it < nt; ++it) {
        int kk0 = kkbeg + it * 64;
        int more = (it + 1 < nt);

        // stage K(t+1) -> lK[cur^1]; in flight across the whole compute phase
        if (more) {
            #pragma unroll
            for (int i = 0; i < 4; ++i) {
                int id = i * 256 + t;
                int m = id >> 4, kgp = id & 15;
                gl2lds16(Kh + base + (size_t)(kk0 + 64 + m) * HD + ((kgp ^ (m & 7)) << 3),
                         &lK[cur ^ 1][id * 8]);
            }
        }

        // QK^T: sf[qt][kt] — all 64 keys for this wave's 32 q rows
        f32x4 sf[2][4] = {};
        __builtin_amdgcn_s_setprio(1);
        #pragma unroll
        for (int ks = 0; ks < 4; ++ks) {
            int kg = ks * 4 + q4;
            bf16x8 af[4];
            #pragma unroll
            for (int kt = 0; kt < 4; ++kt) {
                int row = kt * 16 + c;
                af[kt] = *(bf16x8*)&lK[cur][row * 128 + ((kg ^ (row & 7)) << 3)];
            }
            #pragma unroll
            for (int qt = 0; qt < 2; ++qt)
                #pragma unroll
                for (int kt = 0; kt < 4; ++kt)
                    sf[qt][kt] = __builtin_amdgcn_mfma_f32_16x16x32_bf16(
                        af[kt], qf[qt][ks], sf[qt][kt], 0, 0, 0);
        }
        __builtin_amdgcn_s_setprio(0);

        // fixed-M softmax + in-register P->B-frag redistribution.
        bf16x8 bp[2][2];
        #pragma unroll
        for (int qt = 0; qt < 2; ++qt) {
            unsigned dlo[4], dhi[4];
            float lt = 0.f;
            #pragma unroll
            for (int kt = 0; kt < 4; ++kt) {
                float p0 = exp2f(sf[qt][kt][0]);
                float p1 = exp2f(sf[qt][kt][1]);
                float p2 = exp2f(sf[qt][kt][2]);
                float p3 = exp2f(sf[qt][kt][3]);
                lt += (p0 + p1) + (p2 + p3);
                asm("v_cvt_pk_bf16_f32 %0, %1, %2" : "=v"(dlo[kt]) : "v"(p0), "v"(p1));
                asm("v_cvt_pk_bf16_f32 %0, %1, %2" : "=v"(dhi[kt]) : "v"(p2), "v"(p3));
            }
            lrun[qt] += lt;            // lane-partial; cross-lane reduce deferred
            #pragma unroll
            for (int ksv = 0; ksv < 2; ++ksv) {
                unsigned x0 = dlo[2 * ksv], y0 = dlo[2 * ksv + 1];
                unsigned x1 = dhi[2 * ksv], y1 = dhi[2 * ksv + 1];
                asm("v_permlane32_swap_b32 %0, %1" : "+v"(x0), "+v"(y0));
                asm("v_permlane16_swap_b32 %0, %1" : "+v"(x0), "+v"(y0));
                asm("v_permlane32_swap_b32 %0, %1" : "+v"(x1), "+v"(y1));
                asm("v_permlane16_swap_b32 %0, %1" : "+v"(x1), "+v"(y1));
                uint4v u; u[0] = x0; u[1] = x1; u[2] = y0; u[3] = y1;
                bp[qt][ksv] = __builtin_bit_cast(bf16x8, u);
            }
        }

        // mid barrier: VT(t) must be landed; K(t+1) stays in flight
        if (more) asm volatile("s_waitcnt vmcnt(4)" ::: "memory");
        else      asm volatile("s_waitcnt vmcnt(0)" ::: "memory");
        __builtin_amdgcn_s_barrier();
        __builtin_amdgcn_sched_barrier(0);

        // PV: of[dt][qt] += VT[d][k] @ P[k][q]  (P from registers)
        __builtin_amdgcn_s_setprio(1);
        #pragma unroll
        for (int ksv = 0; ksv < 2; ++ksv) {
            int kg = ksv * 4 + q4;
            bf16x8 av[8];
            #pragma unroll
            for (int dt = 0; dt < 8; ++dt) {
                int row = dt * 16 + c;
                av[dt] = *(bf16x8*)&lVT[row * 64 + ((kg ^ (row & 7)) << 3)];
            }
            #pragma unroll
            for (int qt = 0; qt < 2; ++qt)
                #pragma unroll
                for (int dt = 0; dt < 8; ++dt)
                    of[dt][qt] = __builtin_amdgcn_mfma_f32_16x16x32_bf16(
                        av[dt], bp[qt][ksv], of[dt][qt], 0, 0, 0);
        }
        __builtin_amdgcn_s_setprio(0);

        // end barrier: K(t+1) landed; all waves done reading lVT
        asm volatile("s_waitcnt vmcnt(0)" ::: "memory");
        __builtin_amdgcn_s_barrier();
        __builtin_amdgcn_sched_barrier(0);

        if (more) {
            #pragma unroll
            for (int i = 0; i < 4; ++i) {
                int id = i * 256 + t;
                int mv = id >> 3, kgvp = id & 7;
                gl2lds16(VTg + base + (size_t)mv * S_ + kk0 + 64 + ((kgvp ^ (mv & 7)) << 3),
                         &lVT[id * 8]);
            }
        }
        cur ^= 1;
    }

    // deferred cross-lane l reduction (sum over q4 groups for fixed q=c)
    #pragma unroll
    for (int qt = 0; qt < 2; ++qt) {
        lrun[qt] += __shfl_xor(lrun[qt], 16);
        lrun[qt] += __shfl_xor(lrun[qt], 32);
    }

    if (nsplit > 1) {
        #pragma unroll
        for (int qt = 0; qt < 2; ++qt) {
            int s = s0 + wv * 32 + qt * 16 + c;
            size_t rowu = (size_t)(z * 8 + bh) * S_ + s;
            float* up = U + rowu * HD;
            #pragma unroll
            for (int dt = 0; dt < 8; ++dt)
                *(f32x4*)&up[dt * 16 + q4 * 4] = of[dt][qt];
            if (q4 == 0) ML[rowu] = lrun[qt];
        }
    } else {
        int b = bh >> 2, h = bh & 3;
        #pragma unroll
        for (int qt = 0; qt < 2; ++qt) {
            float inv = 1.0f / lrun[qt];
            int s = s0 + wv * 32 + qt * 16 + c;
            short* dst = AO + ((size_t)(b * S_ + s)) * D_MODEL + h * HD;
            #pragma unroll
            for (int dt = 0; dt < 8; ++dt) {
                uint2v ov;
                ov[0] = pk2bf(of[dt][qt][0] * inv, of[dt][qt][1] * inv);
                ov[1] = pk2bf(of[dt][qt][2] * inv, of[dt][qt][3] * inv);
                *(uint2v*)(dst + dt * 16 + q4 * 4) = ov;
            }
        }
    }
}

// ---------------------------------------------------------------------------
// Combine nsplit K-split partials (fixed-M): O = sum(Uz)/sum(lz) -> bf16 AO
// ---------------------------------------------------------------------------
__global__ __launch_bounds__(256) void combine_kernel(
    const float* __restrict__ U, const float* __restrict__ ML,
    short* __restrict__ AO, int nsplit)
{
    int row = blockIdx.x * 8 + (threadIdx.x >> 5);
    int d4 = (threadIdx.x & 31) * 4;
    const int R = 8 * S_;
    float l = 0.f;
    f32x4 u = {0.f, 0.f, 0.f, 0.f};
    for (int zz = 0; zz < nsplit; ++zz) {
        l += ML[(size_t)zz * R + row];
        f32x4 uz = *(const f32x4*)&U[((size_t)zz * R + row) * HD + d4];
        u += uz;
    }
    float inv = 1.0f / l;
    uint2v o;
    o[0] = pk2bf(u[0] * inv, u[1] * inv);
    o[1] = pk2bf(u[2] * inv, u[3] * inv);
    int bh = row >> 12, s = row & 4095;
    int b = bh >> 2, h = bh & 3;
    *(uint2v*)&AO[((size_t)(b * S_ + s)) * D_MODEL + h * HD + d4] = o;
}

// ---------------------------------------------------------------------------
extern "C" void kernel_launch(void* const* d_in, const int* in_sizes, int n_in,
                              void* d_out, int out_size, void* d_ws, size_t ws_size,
                              hipStream_t stream) {
    const float* q  = (const float*)d_in[0];
    const float* k  = (const float*)d_in[1];
    const float* v  = (const float*)d_in[2];
    const float* Wq = (const float*)d_in[3];
    const float* bq = (const float*)d_in[4];
    const float* Wk = (const float*)d_in[5];
    const float* bk = (const float*)d_in[6];
    const float* Wv = (const float*)d_in[7];
    const float* bv = (const float*)d_in[8];
    const float* Wo = (const float*)d_in[9];
    const float* bo = (const float*)d_in[10];

    const size_t HS = (size_t)2 * NHEAD * S_ * HD;      // 4,194,304 elems
    const size_t NBIG = HS;
    const size_t NW = (size_t)D_MODEL * D_MODEL;
    const size_t R = (size_t)8 * S_;                     // U rows per split

    char* wsb = (char*)d_ws;
    short* Qh = (short*)wsb;
    short* Kh = Qh + HS;
    short* VT = Kh + HS;
    short* AO = VT + HS;
    char* r2 = wsb + 4 * HS * 2;
    short* qb  = (short*)r2;
    short* kb  = qb + NBIG;
    short* vb  = kb + NBIG;
    short* Wqb = vb + NBIG;
    short* Wkb = Wqb + NW;
    short* Wvb = Wkb + NW;
    float* U   = (float*)r2;

    // nsplit=2 preferred: same 2-blocks/CU residency as 4, half the U traffic
    int nsplit = 1;
    size_t r2sz = 3 * NBIG * 2 + 3 * NW * 2;            // bf16 temps floor
    {
        int cand = 2;
        size_t r2c = (size_t)cand * R * HD * 4;         // U bytes
        if (r2c < 3 * NBIG * 2 + 3 * NW * 2) r2c = 3 * NBIG * 2 + 3 * NW * 2;
        size_t need = 4 * HS * 2 + r2c + (size_t)cand * R * 4 + NW * 2;
        if (ws_size >= need) { nsplit = cand; r2sz = r2c; }
    }
    float* ML  = (float*)(r2 + r2sz);
    short* Wob = (short*)((char*)ML + (size_t)nsplit * R * 4);
    int kkspan = S_ / nsplit;

    dim3 blk(256);
    convert_kernel<<<dim3(2048, 7), blk, 0, stream>>>(
        q, k, v, Wq, Wk, Wv, Wo, qb, kb, vb, Wqb, Wkb, Wvb, Wob);
    qkv_kernel<<<dim3(128, 4, 3), blk, 0, stream>>>(
        qb, kb, vb, Wqb, Wkb, Wvb, bq, bk, bv, Qh, Kh, VT);
    flash_kernel<<<dim3(8, 32, nsplit), blk, 0, stream>>>(
        Qh, Kh, VT, AO, U, ML, nsplit, kkspan);
    if (nsplit > 1)
        combine_kernel<<<dim3(S_), blk, 0, stream>>>(U, ML, AO, nsplit);
    outproj_kernel<<<dim3(128, 4), blk, 0, stream>>>(AO, Wob, bo, (float*)d_out);
}

// Round 7
// 224.165 us; speedup vs baseline: 1.1381x; 1.0188x over previous
//
#include <hip/hip_runtime.h>

// MultiheadAttention: B=2, S=4096, D_MODEL=512, NHEAD=4, HEAD_DIM=128
// R17: flash pipelined PV (T15): VT double-buffered (LDS 64 KB, still 2
//   blocks/CU — regs bind first), ONE barrier/tile (mid barrier existed only
//   to protect single-buf VT). Iter t: stage K(t+1),VT(t); QK(t); PV(t-1);
//   SM(t). PV(t-1) is independent of SM(t) -> MFMA/VALU overlap in-wave.
//   bpA/bpB static double-state via 2x-unrolled loop (no dyn indexing).
// Keeps: R16 qkv/outproj 2-phase pipeline, nsplit=2, in-register P
//   (cvt_pk+permlane), fixed-M softmax (Q pre-scaled by 1/sqrt(hd)*log2e),
//   DMA staging w/ global-side XOR swizzle, bh-major grid.

#define D_MODEL 512
#define NHEAD 4
#define HD 128
#define S_ 4096

typedef __attribute__((ext_vector_type(8))) short bf16x8;
typedef __attribute__((ext_vector_type(4))) short bf16x4;
typedef __attribute__((ext_vector_type(4))) float f32x4;
typedef __attribute__((ext_vector_type(2))) unsigned uint2v;
typedef __attribute__((ext_vector_type(4))) unsigned uint4v;

#define SCQ (0.08838834764831845f * 1.4426950408889634f)

__device__ __forceinline__ short f2bf(float f) {
    unsigned u = __builtin_bit_cast(unsigned, f);
    u += 0x7fffu + ((u >> 16) & 1u);
    return (short)(u >> 16);
}
__device__ __forceinline__ unsigned pk2bf(float a, float b) {
    unsigned ua = __builtin_bit_cast(unsigned, a);
    ua += 0x7fffu + ((ua >> 16) & 1u);
    unsigned ub = __builtin_bit_cast(unsigned, b);
    ub += 0x7fffu + ((ub >> 16) & 1u);
    return (ua >> 16) | (ub & 0xffff0000u);
}
__device__ __forceinline__ void gl2lds16(const short* g, short* l) {
    __builtin_amdgcn_global_load_lds(
        (const __attribute__((address_space(1))) void*)g,
        (__attribute__((address_space(3))) void*)l, 16, 0, 0);
}

// ---------------------------------------------------------------------------
// Bulk fp32 -> bf16 conversion. grid.y selects segment; 8 elems/thread.
// ---------------------------------------------------------------------------
__global__ __launch_bounds__(256) void convert_kernel(
    const float* __restrict__ s0, const float* __restrict__ s1,
    const float* __restrict__ s2, const float* __restrict__ s3,
    const float* __restrict__ s4, const float* __restrict__ s5,
    const float* __restrict__ s6,
    short* __restrict__ d0, short* __restrict__ d1, short* __restrict__ d2,
    short* __restrict__ d3, short* __restrict__ d4, short* __restrict__ d5,
    short* __restrict__ d6)
{
    int seg = blockIdx.y;
    const float* src; short* dst; int n;
    const int NBIG = 2 * S_ * D_MODEL;
    const int NW = D_MODEL * D_MODEL;
    switch (seg) {
        case 0: src = s0; dst = d0; n = NBIG; break;
        case 1: src = s1; dst = d1; n = NBIG; break;
        case 2: src = s2; dst = d2; n = NBIG; break;
        case 3: src = s3; dst = d3; n = NW; break;
        case 4: src = s4; dst = d4; n = NW; break;
        case 5: src = s5; dst = d5; n = NW; break;
        default: src = s6; dst = d6; n = NW; break;
    }
    int idx = (blockIdx.x * 256 + threadIdx.x) * 8;
    if (idx >= n) return;
    float4 a = *(const float4*)(src + idx);
    float4 b = *(const float4*)(src + idx + 4);
    uint4v o;
    o[0] = pk2bf(a.x, a.y); o[1] = pk2bf(a.z, a.w);
    o[2] = pk2bf(b.x, b.y); o[3] = pk2bf(b.z, b.w);
    *(uint4v*)(dst + idx) = o;
}

// ---------------------------------------------------------------------------
// Fused QKV projection (bf16 in). 64x128 tiles, BK=64, A+B double-buffered,
// one barrier per K-step, DMA in flight across compute.
// z=0 -> Q[b][h][s][d] (PRE-SCALED by SCQ), z=1 -> K, z=2 -> V^T.
// ---------------------------------------------------------------------------
__global__ __launch_bounds__(256) void qkv_kernel(
    const short* __restrict__ qb, const short* __restrict__ kb,
    const short* __restrict__ vb,
    const short* __restrict__ Wqb, const short* __restrict__ Wkb,
    const short* __restrict__ Wvb,
    const float* __restrict__ bq, const float* __restrict__ bk,
    const float* __restrict__ bv,
    short* __restrict__ Qh, short* __restrict__ Kh, short* __restrict__ VT)
{
    __shared__ short smem[24576];           // 48 KB
    int z = blockIdx.z;
    const short* A    = (z == 0) ? qb  : (z == 1) ? kb  : vb;
    const short* W    = (z == 0) ? Wqb : (z == 1) ? Wkb : Wvb;
    const float* bias = (z == 0) ? bq  : (z == 1) ? bk  : bv;
    short* out        = (z == 0) ? Qh  : (z == 1) ? Kh  : VT;
    int vmode = (z == 2);
    float osc = (z == 0) ? SCQ : 1.0f;      // Q pre-scale

    int t = threadIdx.x;
    int wv = t >> 6, ln = t & 63, q4 = ln >> 4, c = ln & 15;
    int m0 = blockIdx.x * 64, n0 = blockIdx.y * 128;
    f32x4 acc[8] = {};

    {
        short* lAd = smem;
        short* lBd = smem + 8192;
        #pragma unroll
        for (int i = 0; i < 2; ++i) {
            int id = i * 256 + t;
            int m = id >> 3, kgp = id & 7;
            gl2lds16(A + (size_t)(m0 + m) * 512 + ((kgp ^ (m & 7)) << 3), &lAd[id * 8]);
        }
        #pragma unroll
        for (int i = 0; i < 4; ++i) {
            int id = i * 256 + t;
            int n = id >> 3, kgp = id & 7;
            gl2lds16(W + (size_t)(n0 + n) * 512 + ((kgp ^ (n & 7)) << 3), &lBd[id * 8]);
        }
    }
    asm volatile("s_waitcnt vmcnt(0)" ::: "memory");
    __builtin_amdgcn_s_barrier();
    __builtin_amdgcn_sched_barrier(0);

    int cur = 0;
    for (int k0 = 0; k0 < 512; k0 += 64) {
        int more = (k0 < 448);
        if (more) {
            short* lAd = smem + (cur ^ 1) * 4096;
            short* lBd = smem + 8192 + (cur ^ 1) * 8192;
            int kn = k0 + 64;
            #pragma unroll
            for (int i = 0; i < 2; ++i) {
                int id = i * 256 + t;
                int m = id >> 3, kgp = id & 7;
                gl2lds16(A + (size_t)(m0 + m) * 512 + kn + ((kgp ^ (m & 7)) << 3), &lAd[id * 8]);
            }
            #pragma unroll
            for (int i = 0; i < 4; ++i) {
                int id = i * 256 + t;
                int n = id >> 3, kgp = id & 7;
                gl2lds16(W + (size_t)(n0 + n) * 512 + kn + ((kgp ^ (n & 7)) << 3), &lBd[id * 8]);
            }
        }
        short* lAc = smem + cur * 4096;
        short* lBc = smem + 8192 + cur * 8192;
        __builtin_amdgcn_s_setprio(1);
        #pragma unroll
        for (int ks = 0; ks < 2; ++ks) {
            int kg = ks * 4 + q4;
            int m = wv * 16 + c;
            bf16x8 af = *(bf16x8*)&lAc[m * 64 + ((kg ^ (m & 7)) << 3)];
            bf16x8 bfr[8];
            #pragma unroll
            for (int nt = 0; nt < 8; ++nt) {
                int n = nt * 16 + c;
                bfr[nt] = *(bf16x8*)&lBc[n * 64 + ((kg ^ (n & 7)) << 3)];
            }
            #pragma unroll
            for (int nt = 0; nt < 8; ++nt)
                acc[nt] = __builtin_amdgcn_mfma_f32_16x16x32_bf16(af, bfr[nt], acc[nt], 0, 0, 0);
        }
        __builtin_amdgcn_s_setprio(0);
        if (more) asm volatile("s_waitcnt vmcnt(0)" ::: "memory");
        __builtin_amdgcn_s_barrier();
        __builtin_amdgcn_sched_barrier(0);
        cur ^= 1;
    }

    if (vmode == 0) {
        const int TS = 136;
        short* lT = smem;                    // 64 x 136 = 17408 B
        for (int nt = 0; nt < 8; ++nt) {
            float bv_ = bias[n0 + nt * 16 + c];
            for (int r = 0; r < 4; ++r) {
                int srow = wv * 16 + q4 * 4 + r;
                lT[srow * TS + nt * 16 + c] = f2bf((acc[nt][r] + bv_) * osc);
            }
        }
        __syncthreads();
        int bb = m0 >> 12, sbase = m0 & 4095, h = blockIdx.y;
        for (int i = 0; i < 4; ++i) {
            int id = i * 256 + t;
            int row = id >> 4, g = id & 15;
            bf16x8 vv = *(bf16x8*)&lT[row * TS + g * 8];
            *(bf16x8*)&out[((size_t)((bb * NHEAD + h) * S_ + sbase + row)) * HD + g * 8] = vv;
        }
    } else {
        short* lB0 = smem + 8192;
        for (int nt = 0; nt < 8; ++nt) {
            int d = nt * 16 + c;
            float bv_ = bias[n0 + d];
            uint2v pv;
            pv[0] = pk2bf(acc[nt][0] + bv_, acc[nt][1] + bv_);
            pv[1] = pk2bf(acc[nt][2] + bv_, acc[nt][3] + bv_);
            int gr = wv * 4 + q4;
            *(uint2v*)&lB0[d * 64 + ((gr ^ (d & 15)) << 2)] = pv;
        }
        __syncthreads();
        int bb = m0 >> 12, sbase = m0 & 4095, h = blockIdx.y;
        for (int i = 0; i < 8; ++i) {
            int id = i * 256 + t;
            int d = id >> 4, grl = id & 15;
            bf16x4 v = *(bf16x4*)&lB0[d * 64 + ((grl ^ (d & 15)) << 2)];
            *(bf16x4*)&out[((size_t)((bb * NHEAD + h) * HD + d)) * S_ + sbase + grl * 4] = v;
        }
    }
}

// ---------------------------------------------------------------------------
// Output projection (bf16 AO, bf16 Wo): 64x128 tiles, BK=64, A+B dbuf,
// one barrier per K-step.
// ---------------------------------------------------------------------------
__global__ __launch_bounds__(256) void outproj_kernel(
    const short* __restrict__ A, const short* __restrict__ W,
    const float* __restrict__ bias, float* __restrict__ out)
{
    __shared__ short smem[24576];           // 48 KB
    int t = threadIdx.x;
    int wv = t >> 6, ln = t & 63, q4 = ln >> 4, c = ln & 15;
    int m0 = blockIdx.x * 64, n0 = blockIdx.y * 128;
    f32x4 acc[8] = {};

    {
        short* lAd = smem;
        short* lBd = smem + 8192;
        #pragma unroll
        for (int i = 0; i < 2; ++i) {
            int id = i * 256 + t;
            int m = id >> 3, kgp = id & 7;
            gl2lds16(A + (size_t)(m0 + m) * 512 + ((kgp ^ (m & 7)) << 3), &lAd[id * 8]);
        }
        #pragma unroll
        for (int i = 0; i < 4; ++i) {
            int id = i * 256 + t;
            int n = id >> 3, kgp = id & 7;
            gl2lds16(W + (size_t)(n0 + n) * 512 + ((kgp ^ (n & 7)) << 3), &lBd[id * 8]);
        }
    }
    asm volatile("s_waitcnt vmcnt(0)" ::: "memory");
    __builtin_amdgcn_s_barrier();
    __builtin_amdgcn_sched_barrier(0);

    int cur = 0;
    for (int k0 = 0; k0 < 512; k0 += 64) {
        int more = (k0 < 448);
        if (more) {
            short* lAd = smem + (cur ^ 1) * 4096;
            short* lBd = smem + 8192 + (cur ^ 1) * 8192;
            int kn = k0 + 64;
            #pragma unroll
            for (int i = 0; i < 2; ++i) {
                int id = i * 256 + t;
                int m = id >> 3, kgp = id & 7;
                gl2lds16(A + (size_t)(m0 + m) * 512 + kn + ((kgp ^ (m & 7)) << 3), &lAd[id * 8]);
            }
            #pragma unroll
            for (int i = 0; i < 4; ++i) {
                int id = i * 256 + t;
                int n = id >> 3, kgp = id & 7;
                gl2lds16(W + (size_t)(n0 + n) * 512 + kn + ((kgp ^ (n & 7)) << 3), &lBd[id * 8]);
            }
        }
        short* lAc = smem + cur * 4096;
        short* lBc = smem + 8192 + cur * 8192;
        __builtin_amdgcn_s_setprio(1);
        #pragma unroll
        for (int ks = 0; ks < 2; ++ks) {
            int kg = ks * 4 + q4;
            int m = wv * 16 + c;
            bf16x8 af = *(bf16x8*)&lAc[m * 64 + ((kg ^ (m & 7)) << 3)];
            bf16x8 bfr[8];
            #pragma unroll
            for (int nt = 0; nt < 8; ++nt) {
                int n = nt * 16 + c;
                bfr[nt] = *(bf16x8*)&lBc[n * 64 + ((kg ^ (n & 7)) << 3)];
            }
            #pragma unroll
            for (int nt = 0; nt < 8; ++nt)
                acc[nt] = __builtin_amdgcn_mfma_f32_16x16x32_bf16(af, bfr[nt], acc[nt], 0, 0, 0);
        }
        __builtin_amdgcn_s_setprio(0);
        if (more) asm volatile("s_waitcnt vmcnt(0)" ::: "memory");
        __builtin_amdgcn_s_barrier();
        __builtin_amdgcn_sched_barrier(0);
        cur ^= 1;
    }

    for (int nt = 0; nt < 8; ++nt) {
        int col = n0 + nt * 16 + c;
        float bv_ = bias[col];
        for (int r = 0; r < 4; ++r) {
            int mrow = m0 + wv * 16 + q4 * 4 + r;
            out[(size_t)mrow * 512 + col] = acc[nt][r] + bv_;
        }
    }
}

// ---------------------------------------------------------------------------
// Flash helpers
// ---------------------------------------------------------------------------
__device__ __forceinline__ void stage_k(const short* __restrict__ Kh, size_t base,
                                        int kk, short* dst, int t) {
    #pragma unroll
    for (int i = 0; i < 4; ++i) {
        int id = i * 256 + t;
        int m = id >> 4, kgp = id & 15;
        gl2lds16(Kh + base + (size_t)(kk + m) * HD + ((kgp ^ (m & 7)) << 3), &dst[id * 8]);
    }
}
__device__ __forceinline__ void stage_vt(const short* __restrict__ VTg, size_t base,
                                         int kk, short* dst, int t) {
    #pragma unroll
    for (int i = 0; i < 4; ++i) {
        int id = i * 256 + t;
        int mv = id >> 3, kgvp = id & 7;
        gl2lds16(VTg + base + (size_t)mv * S_ + kk + ((kgvp ^ (mv & 7)) << 3), &dst[id * 8]);
    }
}
__device__ __forceinline__ void qk_tile(const short* kb, const bf16x8 (&qf)[2][4],
                                        int q4, int c, f32x4 (&sf)[2][4]) {
    #pragma unroll
    for (int ks = 0; ks < 4; ++ks) {
        int kg = ks * 4 + q4;
        bf16x8 af[4];
        #pragma unroll
        for (int kt = 0; kt < 4; ++kt) {
            int row = kt * 16 + c;
            af[kt] = *(bf16x8*)&kb[row * 128 + ((kg ^ (row & 7)) << 3)];
        }
        #pragma unroll
        for (int qt = 0; qt < 2; ++qt)
            #pragma unroll
            for (int kt = 0; kt < 4; ++kt)
                sf[qt][kt] = __builtin_amdgcn_mfma_f32_16x16x32_bf16(
                    af[kt], qf[qt][ks], sf[qt][kt], 0, 0, 0);
    }
}
__device__ __forceinline__ void pv_tile(const short* vb, const bf16x8 (&bp)[2][2],
                                        int q4, int c, f32x4 (&of)[8][2]) {
    #pragma unroll
    for (int ksv = 0; ksv < 2; ++ksv) {
        int kg = ksv * 4 + q4;
        bf16x8 av[8];
        #pragma unroll
        for (int dt = 0; dt < 8; ++dt) {
            int row = dt * 16 + c;
            av[dt] = *(bf16x8*)&vb[row * 64 + ((kg ^ (row & 7)) << 3)];
        }
        #pragma unroll
        for (int qt = 0; qt < 2; ++qt)
            #pragma unroll
            for (int dt = 0; dt < 8; ++dt)
                of[dt][qt] = __builtin_amdgcn_mfma_f32_16x16x32_bf16(
                    av[dt], bp[qt][ksv], of[dt][qt], 0, 0, 0);
    }
}
__device__ __forceinline__ void sm_tile(const f32x4 (&sf)[2][4], float (&lrun)[2],
                                        bf16x8 (&bp)[2][2]) {
    // Lane(q4,c) after QK^T: P[key=kt*16+q4*4+r][q=c] in sf[qt][kt][r].
    // Target B-frag: lane(q4,c) holds keys ksv*32+q4*8..+7.
    // p32swap then p16swap on cvt_pk'd dwords.
    #pragma unroll
    for (int qt = 0; qt < 2; ++qt) {
        unsigned dlo[4], dhi[4];
        float lt = 0.f;
        #pragma unroll
        for (int kt = 0; kt < 4; ++kt) {
            float p0 = exp2f(sf[qt][kt][0]);
            float p1 = exp2f(sf[qt][kt][1]);
            float p2 = exp2f(sf[qt][kt][2]);
            float p3 = exp2f(sf[qt][kt][3]);
            lt += (p0 + p1) + (p2 + p3);
            asm("v_cvt_pk_bf16_f32 %0, %1, %2" : "=v"(dlo[kt]) : "v"(p0), "v"(p1));
            asm("v_cvt_pk_bf16_f32 %0, %1, %2" : "=v"(dhi[kt]) : "v"(p2), "v"(p3));
        }
        lrun[qt] += lt;            // lane-partial; cross-lane reduce deferred
        #pragma unroll
        for (int ksv = 0; ksv < 2; ++ksv) {
            unsigned x0 = dlo[2 * ksv], y0 = dlo[2 * ksv + 1];
            unsigned x1 = dhi[2 * ksv], y1 = dhi[2 * ksv + 1];
            asm("v_permlane32_swap_b32 %0, %1" : "+v"(x0), "+v"(y0));
            asm("v_permlane16_swap_b32 %0, %1" : "+v"(x0), "+v"(y0));
            asm("v_permlane32_swap_b32 %0, %1" : "+v"(x1), "+v"(y1));
            asm("v_permlane16_swap_b32 %0, %1" : "+v"(x1), "+v"(y1));
            uint4v u; u[0] = x0; u[1] = x1; u[2] = y0; u[3] = y1;
            bp[qt][ksv] = __builtin_bit_cast(bf16x8, u);
        }
    }
}

#define FLASH_BAR() do { \
    asm volatile("s_waitcnt vmcnt(0)" ::: "memory"); \
    __builtin_amdgcn_s_barrier(); \
    __builtin_amdgcn_sched_barrier(0); } while (0)

// ---------------------------------------------------------------------------
// Flash attention: 4-wave q-split, K dbuf + VT dbuf, PV lagged one tile,
// in-register P, ONE barrier/tile. grid = (bh 8, qtile 32, z nsplit)
// ---------------------------------------------------------------------------
__global__ __launch_bounds__(256, 2) void flash_kernel(
    const short* __restrict__ Qh, const short* __restrict__ Kh,
    const short* __restrict__ VTg, short* __restrict__ AO,
    float* __restrict__ U, float* __restrict__ ML, int nsplit, int kkspan)
{
    __shared__ short lK[2][64 * 128];    // 2 x 16 KB
    __shared__ short lVT[2][128 * 64];   // 2 x 16 KB
    int t = threadIdx.x;
    int wv = t >> 6, ln = t & 63, q4 = ln >> 4, c = ln & 15;
    int bh = blockIdx.x;
    int s0 = blockIdx.y * 128;
    int z = blockIdx.z;
    const size_t base = (size_t)bh * S_ * HD;

    // Q fragments: wave wv owns q rows [s0+32*wv, +32)
    bf16x8 qf[2][4];
    #pragma unroll
    for (int qt = 0; qt < 2; ++qt) {
        int s = s0 + wv * 32 + qt * 16 + c;
        const short* qp = Qh + base + (size_t)s * HD + q4 * 8;
        #pragma unroll
        for (int ks = 0; ks < 4; ++ks)
            qf[qt][ks] = *(const bf16x8*)(qp + ks * 32);
    }

    f32x4 of[8][2] = {};      // of[dt][qt]: d = dt*16+q4*4+r, q = c
    float lrun[2] = {};
    bf16x8 bpA[2][2], bpB[2][2];

    int kkbeg = z * kkspan;
    int ntl = kkspan >> 6;    // even (32 or 64)

    // prologue: K(0) -> lK[0]
    stage_k(Kh, base, kkbeg, &lK[0][0], t);
    FLASH_BAR();

    // iter 0: stage K(1)->lK[1], VT(0)->lVT[0]; QK(0); SM->bpA (no PV)
    {
        stage_k(Kh, base, kkbeg + 64, &lK[1][0], t);
        stage_vt(VTg, base, kkbeg, &lVT[0][0], t);
        f32x4 sf[2][4] = {};
        __builtin_amdgcn_s_setprio(1);
        qk_tile(&lK[0][0], qf, q4, c, sf);
        __builtin_amdgcn_s_setprio(0);
        sm_tile(sf, lrun, bpA);
        FLASH_BAR();
    }

    // iters 1..ntl-2 in pairs (odd: read bpA write bpB; even: read bpB write bpA)
    for (int j = 1; j + 1 < ntl; j += 2) {
        {   // iter j (odd): K(j) in lK[1], VT(j-1) in lVT[0]
            int kk0 = kkbeg + j * 64;
            stage_k(Kh, base, kk0 + 64, &lK[0][0], t);
            stage_vt(VTg, base, kk0, &lVT[1][0], t);
            f32x4 sf[2][4] = {};
            __builtin_amdgcn_s_setprio(1);
            qk_tile(&lK[1][0], qf, q4, c, sf);
            pv_tile(&lVT[0][0], bpA, q4, c, of);
            __builtin_amdgcn_s_setprio(0);
            sm_tile(sf, lrun, bpB);
            FLASH_BAR();
        }
        {   // iter j+1 (even): K in lK[0], VT(j) in lVT[1]
            int kk0 = kkbeg + (j + 1) * 64;
            if (j + 2 < ntl) stage_k(Kh, base, kk0 + 64, &lK[1][0], t);
            stage_vt(VTg, base, kk0, &lVT[0][0], t);
            f32x4 sf[2][4] = {};
            __builtin_amdgcn_s_setprio(1);
            qk_tile(&lK[0][0], qf, q4, c, sf);
            pv_tile(&lVT[1][0], bpB, q4, c, of);
            __builtin_amdgcn_s_setprio(0);
            sm_tile(sf, lrun, bpA);
            FLASH_BAR();
        }
    }

    // last iter = ntl-1 (odd): K in lK[1], VT(ntl-2) in lVT[0]; no K stage
    {
        int kk0 = kkbeg + (ntl - 1) * 64;
        stage_vt(VTg, base, kk0, &lVT[1][0], t);
        f32x4 sf[2][4] = {};
        __builtin_amdgcn_s_setprio(1);
        qk_tile(&lK[1][0], qf, q4, c, sf);
        pv_tile(&lVT[0][0], bpA, q4, c, of);
        __builtin_amdgcn_s_setprio(0);
        sm_tile(sf, lrun, bpB);
        FLASH_BAR();
    }

    // epilogue PV: tile ntl-1, VT(ntl-1) in lVT[1], P in bpB
    __builtin_amdgcn_s_setprio(1);
    pv_tile(&lVT[1][0], bpB, q4, c, of);
    __builtin_amdgcn_s_setprio(0);

    // deferred cross-lane l reduction (sum over q4 groups for fixed q=c)
    #pragma unroll
    for (int qt = 0; qt < 2; ++qt) {
        lrun[qt] += __shfl_xor(lrun[qt], 16);
        lrun[qt] += __shfl_xor(lrun[qt], 32);
    }

    if (nsplit > 1) {
        #pragma unroll
        for (int qt = 0; qt < 2; ++qt) {
            int s = s0 + wv * 32 + qt * 16 + c;
            size_t rowu = (size_t)(z * 8 + bh) * S_ + s;
            float* up = U + rowu * HD;
            #pragma unroll
            for (int dt = 0; dt < 8; ++dt)
                *(f32x4*)&up[dt * 16 + q4 * 4] = of[dt][qt];
            if (q4 == 0) ML[rowu] = lrun[qt];
        }
    } else {
        int b = bh >> 2, h = bh & 3;
        #pragma unroll
        for (int qt = 0; qt < 2; ++qt) {
            float inv = 1.0f / lrun[qt];
            int s = s0 + wv * 32 + qt * 16 + c;
            short* dst = AO + ((size_t)(b * S_ + s)) * D_MODEL + h * HD;
            #pragma unroll
            for (int dt = 0; dt < 8; ++dt) {
                uint2v ov;
                ov[0] = pk2bf(of[dt][qt][0] * inv, of[dt][qt][1] * inv);
                ov[1] = pk2bf(of[dt][qt][2] * inv, of[dt][qt][3] * inv);
                *(uint2v*)(dst + dt * 16 + q4 * 4) = ov;
            }
        }
    }
}

// ---------------------------------------------------------------------------
// Combine nsplit K-split partials (fixed-M): O = sum(Uz)/sum(lz) -> bf16 AO
// ---------------------------------------------------------------------------
__global__ __launch_bounds__(256) void combine_kernel(
    const float* __restrict__ U, const float* __restrict__ ML,
    short* __restrict__ AO, int nsplit)
{
    int row = blockIdx.x * 8 + (threadIdx.x >> 5);
    int d4 = (threadIdx.x & 31) * 4;
    const int R = 8 * S_;
    float l = 0.f;
    f32x4 u = {0.f, 0.f, 0.f, 0.f};
    for (int zz = 0; zz < nsplit; ++zz) {
        l += ML[(size_t)zz * R + row];
        f32x4 uz = *(const f32x4*)&U[((size_t)zz * R + row) * HD + d4];
        u += uz;
    }
    float inv = 1.0f / l;
    uint2v o;
    o[0] = pk2bf(u[0] * inv, u[1] * inv);
    o[1] = pk2bf(u[2] * inv, u[3] * inv);
    int bh = row >> 12, s = row & 4095;
    int b = bh >> 2, h = bh & 3;
    *(uint2v*)&AO[((size_t)(b * S_ + s)) * D_MODEL + h * HD + d4] = o;
}

// ---------------------------------------------------------------------------
extern "C" void kernel_launch(void* const* d_in, const int* in_sizes, int n_in,
                              void* d_out, int out_size, void* d_ws, size_t ws_size,
                              hipStream_t stream) {
    const float* q  = (const float*)d_in[0];
    const float* k  = (const float*)d_in[1];
    const float* v  = (const float*)d_in[2];
    const float* Wq = (const float*)d_in[3];
    const float* bq = (const float*)d_in[4];
    const float* Wk = (const float*)d_in[5];
    const float* bk = (const float*)d_in[6];
    const float* Wv = (const float*)d_in[7];
    const float* bv = (const float*)d_in[8];
    const float* Wo = (const float*)d_in[9];
    const float* bo = (const float*)d_in[10];

    const size_t HS = (size_t)2 * NHEAD * S_ * HD;      // 4,194,304 elems
    const size_t NBIG = HS;
    const size_t NW = (size_t)D_MODEL * D_MODEL;
    const size_t R = (size_t)8 * S_;                     // U rows per split

    char* wsb = (char*)d_ws;
    short* Qh = (short*)wsb;
    short* Kh = Qh + HS;
    short* VT = Kh + HS;
    short* AO = VT + HS;
    char* r2 = wsb + 4 * HS * 2;
    short* qb  = (short*)r2;
    short* kb  = qb + NBIG;
    short* vb  = kb + NBIG;
    short* Wqb = vb + NBIG;
    short* Wkb = Wqb + NW;
    short* Wvb = Wkb + NW;
    float* U   = (float*)r2;

    // nsplit=2 preferred: same 2-blocks/CU residency as 4, half the U traffic
    int nsplit = 1;
    size_t r2sz = 3 * NBIG * 2 + 3 * NW * 2;            // bf16 temps floor
    {
        int cand = 2;
        size_t r2c = (size_t)cand * R * HD * 4;         // U bytes
        if (r2c < 3 * NBIG * 2 + 3 * NW * 2) r2c = 3 * NBIG * 2 + 3 * NW * 2;
        size_t need = 4 * HS * 2 + r2c + (size_t)cand * R * 4 + NW * 2;
        if (ws_size >= need) { nsplit = cand; r2sz = r2c; }
    }
    float* ML  = (float*)(r2 + r2sz);
    short* Wob = (short*)((char*)ML + (size_t)nsplit * R * 4);
    int kkspan = S_ / nsplit;

    dim3 blk(256);
    convert_kernel<<<dim3(2048, 7), blk, 0, stream>>>(
        q, k, v, Wq, Wk, Wv, Wo, qb, kb, vb, Wqb, Wkb, Wvb, Wob);
    qkv_kernel<<<dim3(128, 4, 3), blk, 0, stream>>>(
        qb, kb, vb, Wqb, Wkb, Wvb, bq, bk, bv, Qh, Kh, VT);
    flash_kernel<<<dim3(8, 32, nsplit), blk, 0, stream>>>(
        Qh, Kh, VT, AO, U, ML, nsplit, kkspan);
    if (nsplit > 1)
        combine_kernel<<<dim3(S_), blk, 0, stream>>>(U, ML, AO, nsplit);
    outproj_kernel<<<dim3(128, 4), blk, 0, stream>>>(AO, Wob, bo, (float*)d_out);
}